// Round 1
// baseline (314.589 us; speedup 1.0000x reference)
//
#include <hip/hip_runtime.h>

// DeepSeek MoE gate, fused: logits GEMM (f16 split-precision MFMA, 3 passes)
// + sigmoid+bias + group-limited top-k epilogue.
// T=16384 tokens, E=256 experts, H=7168, groups=8x32, topk_group=4, top_k=8.

#define TTOK 16384
#define EEXP 256
#define HDIM 7168
#define BM 64
#define BK 64
#define NSTEP (HDIM / BK)   // 112
#define NTHR 512
#define LDS_BYTES 81920     // Ahi 8K + Alo 8K + Bhi 32K + Blo 32K (scores 65.8K overlays)

typedef __attribute__((ext_vector_type(4))) float f32x4;
typedef __attribute__((ext_vector_type(4))) _Float16 h4;
typedef __attribute__((ext_vector_type(8))) _Float16 h8;

// ---------------------------------------------------------------------------
// Kernel 1: W[256][7168] f32 -> w_hi (f16) and w_lo2 = (w - w_hi)*2048 (f16)
// ---------------------------------------------------------------------------
__global__ __launch_bounds__(256) void convert_w_kernel(
    const float* __restrict__ W, _Float16* __restrict__ whi,
    _Float16* __restrict__ wlo) {
  int i = blockIdx.x * blockDim.x + threadIdx.x;  // quad id; grid is exact
  f32x4 v = ((const f32x4*)W)[i];
  h4 hi, lo;
#pragma unroll
  for (int j = 0; j < 4; ++j) {
    float x = v[j];
    _Float16 h = (_Float16)x;
    hi[j] = h;
    lo[j] = (_Float16)((x - (float)h) * 2048.0f);  // exact residual, scaled out of denormal range
  }
  *(h4*)(whi + (size_t)i * 4) = hi;
  *(h4*)(wlo + (size_t)i * 4) = lo;
}

// ---------------------------------------------------------------------------
// Kernel 2: fused gate. One WG = 64 tokens x all 256 experts. 8 waves (2x4).
// ---------------------------------------------------------------------------
// LDS f16 tiles are [rows][64] with 16B chunks XOR-swizzled: chunk' = chunk ^ (row&7).
__device__ __forceinline__ int swz_idx(int r, int kchunk) {
  return r * 64 + ((kchunk ^ (r & 7)) << 3);  // f16 element index of chunk base
}

__global__ __launch_bounds__(NTHR) void gate_kernel(
    const float* __restrict__ X, const _Float16* __restrict__ Whi,
    const _Float16* __restrict__ Wlo, const float* __restrict__ bias,
    float* __restrict__ outw, float* __restrict__ outi) {
  extern __shared__ char smem[];
  _Float16* Ahi = (_Float16*)smem;              // [64][64]
  _Float16* Alo = (_Float16*)(smem + 8192);     // [64][64]
  _Float16* Bhi = (_Float16*)(smem + 16384);    // [256][64]
  _Float16* Blo = (_Float16*)(smem + 49152);    // [256][64]
  float (*scores)[EEXP + 1] = (float (*)[EEXP + 1])smem;  // [64][257], overlays staging

  const int tid = threadIdx.x;
  const int lane = tid & 63;
  const int wid = tid >> 6;
  const int wr = wid >> 2;  // 0..1 : 32-token stripe
  const int wc = wid & 3;   // 0..3 : 64-expert stripe

  // --- staging maps ---
  const int ar = tid >> 3;  // A row 0..63
  const int aq = tid & 7;   // two float4 quads: aq and aq+8
  const long arow_base = (long)(blockIdx.x * BM + ar) * HDIM;

  f32x4 ra0, ra1;     // prefetched A (f32)
  h8 rbh[4], rbl[4];  // prefetched B (f16 hi/lo), 4 chunks each

  f32x4 acc1[2][4], acc2[2][4];
#pragma unroll
  for (int m = 0; m < 2; ++m)
#pragma unroll
    for (int n = 0; n < 4; ++n) {
      acc1[m][n] = (f32x4){0.f, 0.f, 0.f, 0.f};
      acc2[m][n] = (f32x4){0.f, 0.f, 0.f, 0.f};
    }

  auto LOAD = [&](int k0) {
    ra0 = *(const f32x4*)(X + arow_base + k0 + aq * 4);
    ra1 = *(const f32x4*)(X + arow_base + k0 + (aq + 8) * 4);
#pragma unroll
    for (int i = 0; i < 4; ++i) {
      int c = tid + i * 512;  // chunk id 0..2047
      int r = c >> 3, cc = c & 7;
      const long off = (long)r * HDIM + k0 + cc * 8;
      rbh[i] = *(const h8*)(Whi + off);
      rbl[i] = *(const h8*)(Wlo + off);
    }
  };

  auto STORE = [&]() {
    h4 h0, l0, h1, l1;
#pragma unroll
    for (int j = 0; j < 4; ++j) {
      float x0 = ra0[j];
      _Float16 hh0 = (_Float16)x0;
      h0[j] = hh0;
      l0[j] = (_Float16)((x0 - (float)hh0) * 2048.0f);
      float x1 = ra1[j];
      _Float16 hh1 = (_Float16)x1;
      h1[j] = hh1;
      l1[j] = (_Float16)((x1 - (float)hh1) * 2048.0f);
    }
    {
      int e0 = ar * 64 + ((((aq >> 1)) ^ (ar & 7)) << 3) + (aq & 1) * 4;
      int q1 = aq + 8;
      int e1 = ar * 64 + ((((q1 >> 1)) ^ (ar & 7)) << 3) + (q1 & 1) * 4;
      *(h4*)(Ahi + e0) = h0;
      *(h4*)(Ahi + e1) = h1;
      *(h4*)(Alo + e0) = l0;
      *(h4*)(Alo + e1) = l1;
    }
#pragma unroll
    for (int i = 0; i < 4; ++i) {
      int c = tid + i * 512;
      int r = c >> 3, cc = c & 7;
      int e = swz_idx(r, cc);
      *(h8*)(Bhi + e) = rbh[i];
      *(h8*)(Blo + e) = rbl[i];
    }
  };

  LOAD(0);
#pragma unroll 1
  for (int kk = 0; kk < NSTEP; ++kk) {
    __syncthreads();  // previous compute's ds_reads done
    STORE();
    __syncthreads();
    if (kk + 1 < NSTEP) LOAD((kk + 1) * BK);  // overlap next-tile HBM with MFMA

#pragma unroll
    for (int s = 0; s < 2; ++s) {
      const int cc = ((s * 32 + (lane >> 4) * 8) >> 3);  // k-chunk 0..7 for this lane
      h8 ah[2], al[2];
#pragma unroll
      for (int m = 0; m < 2; ++m) {
        int r = wr * 32 + m * 16 + (lane & 15);
        int e = swz_idx(r, cc);
        ah[m] = *(h8*)(Ahi + e);
        al[m] = *(h8*)(Alo + e);
      }
#pragma unroll
      for (int n = 0; n < 4; ++n) {
        int r = wc * 64 + n * 16 + (lane & 15);
        int e = swz_idx(r, cc);
        h8 bh = *(h8*)(Bhi + e);
        h8 bl = *(h8*)(Blo + e);
#pragma unroll
        for (int m = 0; m < 2; ++m) {
          acc1[m][n] = __builtin_amdgcn_mfma_f32_16x16x32_f16(ah[m], bh, acc1[m][n], 0, 0, 0);
          acc2[m][n] = __builtin_amdgcn_mfma_f32_16x16x32_f16(ah[m], bl, acc2[m][n], 0, 0, 0);
          acc2[m][n] = __builtin_amdgcn_mfma_f32_16x16x32_f16(al[m], bh, acc2[m][n], 0, 0, 0);
        }
      }
    }
  }

  __syncthreads();  // last ds_reads done before scores overlay staging LDS

  // scores = sigmoid(logit) + bias  -> LDS [64][257]
  // C/D layout (verified m89/m91): col = lane&15, row = (lane>>4)*4 + reg
#pragma unroll
  for (int m = 0; m < 2; ++m)
#pragma unroll
    for (int n = 0; n < 4; ++n) {
      int e = wc * 64 + n * 16 + (lane & 15);
      float b = bias[e];
      int t0 = wr * 32 + m * 16 + (lane >> 4) * 4;
#pragma unroll
      for (int r = 0; r < 4; ++r) {
        float logit = acc1[m][n][r] + acc2[m][n][r] * (1.0f / 2048.0f);
        scores[t0 + r][e] = 1.0f / (1.0f + expf(-logit)) + b;
      }
    }
  __syncthreads();

  // Per-token top-k: 8 tokens per wave, one active lane per token.
  if ((lane & 7) == 0) {
    int t = wid * 8 + (lane >> 3);  // 0..63
    const float* sc = scores[t];

    // group maxima (8 groups x 32)
    float gmax[8];
#pragma unroll
    for (int g = 0; g < 8; ++g) {
      float mx = -1e30f;
      for (int j = 0; j < 32; ++j) mx = fmaxf(mx, sc[g * 32 + j]);
      gmax[g] = mx;
    }
    // top-4 groups (strict > keeps lowest index on ties, matching lax.top_k)
    unsigned selmask = 0;
    for (int it = 0; it < 4; ++it) {
      float best = -1e30f;
      int bi = 0;
      for (int g = 0; g < 8; ++g)
        if (!((selmask >> g) & 1) && gmax[g] > best) {
          best = gmax[g];
          bi = g;
        }
      selmask |= 1u << bi;
    }
    // stable top-8 over masked scores (masked-out groups contribute 0.0)
    float vals[8];
    int idx[8];
#pragma unroll
    for (int j = 0; j < 8; ++j) {
      vals[j] = -1e30f;
      idx[j] = 0;
    }
    for (int e = 0; e < 256; ++e) {
      float v = ((selmask >> (e >> 5)) & 1) ? sc[e] : 0.0f;
      if (v > vals[7]) {
        int p = 7;
        while (p > 0 && v > vals[p - 1]) {
          vals[p] = vals[p - 1];
          idx[p] = idx[p - 1];
          --p;
        }
        vals[p] = v;
        idx[p] = e;
      }
    }
    float ssum = 0.0f;
#pragma unroll
    for (int j = 0; j < 8; ++j) ssum += vals[j];
    float den = ssum + 1e-6f;
    long tg = (long)blockIdx.x * BM + t;
#pragma unroll
    for (int j = 0; j < 8; ++j) {
      outw[tg * 8 + j] = vals[j] / den;
      outi[tg * 8 + j] = (float)idx[j];  // indices written as f32 values
    }
  }
}

extern "C" void kernel_launch(void* const* d_in, const int* in_sizes, int n_in,
                              void* d_out, int out_size, void* d_ws, size_t ws_size,
                              hipStream_t stream) {
  const float* X = (const float*)d_in[0];     // [16384,7168] f32
  const float* W = (const float*)d_in[1];     // [256,7168] f32
  const float* bias = (const float*)d_in[2];  // [256] f32

  _Float16* whi = (_Float16*)d_ws;
  _Float16* wlo = whi + (size_t)EEXP * HDIM;  // needs 7.34 MB of ws

  float* outw = (float*)d_out;                  // [16384,8]
  float* outi = outw + (size_t)TTOK * 8;        // [16384,8] as f32 values

  hipFuncSetAttribute((const void*)gate_kernel,
                      hipFuncAttributeMaxDynamicSharedMemorySize, LDS_BYTES);

  convert_w_kernel<<<(EEXP * HDIM / 4) / 256, 256, 0, stream>>>(W, whi, wlo);
  gate_kernel<<<TTOK / BM, NTHR, LDS_BYTES, stream>>>(X, whi, wlo, bias, outw, outi);
}